// Round 1
// 140.348 us; speedup vs baseline: 1.0405x; 1.0405x over previous
//
#include <hip/hip_runtime.h>

typedef __attribute__((ext_vector_type(8))) short bf16x8;
typedef __attribute__((ext_vector_type(4))) float f32x4;

#define AS1 __attribute__((address_space(1)))
#define AS3 __attribute__((address_space(3)))

__device__ static inline void gl2lds16(const void* g, void* l) {
  // async global->LDS, 16B per lane; HW writes wave-uniform base + lane*16
  __builtin_amdgcn_global_load_lds((const AS1 unsigned int*)g, (AS3 unsigned int*)l, 16, 0, 0);
}

__device__ static inline unsigned short f2bf(float x) {
  unsigned int u = __float_as_uint(x);
  unsigned int r = u + 0x7FFFu + ((u >> 16) & 1u);  // round-to-nearest-even
  return (unsigned short)(r >> 16);
}

// Fused prep (single graph node):
//  bx < 8192   : inputs[16384][1000] f32 -> a[16384][1024] bf16 = 2*inputs (pad 0)
//  bx < 9216   : code_book row cast -> b[1024][1024] bf16 + rowsum[1024]
//  bx >= 9216  : labels normalize (int64-vs-int32 autodetect); bx==9216,t==0 zeroes lin/out
__global__ __launch_bounds__(256) void prep_all_k(
    const float* __restrict__ in, const int* __restrict__ labraw,
    const float* __restrict__ cb, unsigned short* __restrict__ a,
    unsigned short* __restrict__ b, float* __restrict__ rowsum,
    int* __restrict__ labs, float* __restrict__ lin, float* __restrict__ out) {
  const int bx = blockIdx.x, t = threadIdx.x;
  if (bx < 8192) {
    int idx = bx * 256 + t;  // 16384 rows x 128 groups
    int row = idx >> 7, g = idx & 127;
    union { unsigned short u[8]; uint4 v; } pk;
    if (g < 125) {
      const float4* p = (const float4*)(in + (size_t)row * 1000 + g * 8);
      float4 v0 = p[0], v1 = p[1];
      pk.u[0] = f2bf(2.f * v0.x); pk.u[1] = f2bf(2.f * v0.y);
      pk.u[2] = f2bf(2.f * v0.z); pk.u[3] = f2bf(2.f * v0.w);
      pk.u[4] = f2bf(2.f * v1.x); pk.u[5] = f2bf(2.f * v1.y);
      pk.u[6] = f2bf(2.f * v1.z); pk.u[7] = f2bf(2.f * v1.w);
    } else {
      pk.v = make_uint4(0, 0, 0, 0);
    }
    *(uint4*)(a + ((size_t)row << 10) + (g << 3)) = pk.v;
  } else if (bx < 9216) {
    int n = bx - 8192;
    float s = 0.f;
#pragma unroll
    for (int j = 0; j < 4; ++j) {
      int c = t + j * 256;
      float v = 0.f;
      if (n < 1000 && c < 1000) v = cb[(size_t)n * 1000 + c];
      s += v;
      b[((size_t)n << 10) + c] = f2bf(v);
    }
    __shared__ float red[256];
    red[t] = s;
    __syncthreads();
    for (int o = 128; o > 0; o >>= 1) {
      if (t < o) red[t] += red[t + o];
      __syncthreads();
    }
    if (t == 0) rowsum[n] = (n < 1000) ? red[0] : 0.f;
  } else {
    __shared__ int nz;
    if (t == 0) nz = 0;
    __syncthreads();
    if (labraw[2 * t + 1] != 0) atomicAdd(&nz, 1);
    __syncthreads();
    bool is64 = (nz < 32);
    int row = (bx - 9216) * 256 + t;
    labs[row] = is64 ? labraw[2 * row] : labraw[row];
    if (bx == 9216 && t == 0) { lin[0] = 0.f; out[0] = 0.f; }
  }
}

// R9: T3+T4+T5 schedule. Block 256x256, 8 waves (2x4), wave tile 128x64 =
// 8x4 MFMA 16x16x32 bf16 (acc 128 VGPR -> 2 waves/SIMD, m114 co-scheduling).
// BK=32, FOUR-deep circular LDS pipeline (4 x (16KB A + 16KB B) = 128 KB
// dynamic). Per K-tile: 2 phases, each {ds_read subtile | 2 gl_lds stage ->
// barrier -> setprio(1) 16 MFMA setprio(0) -> barrier}. Counted vmcnt(8) at
// tile end only (3 tiles in flight, never drain-0 in loop) - the m218 lever.
// Ledger: prologue tiles 0-2 (12 issues), iter J stages J+3 (4), end wait
// vmcnt(8) lands tile J+1; stage target (J+3)&3=(J-1)&3 whose reads finished
// before iter J-1's trailing barrier -> no WAR race. sched_barrier(0) after
// each trailing barrier pins ds_reads to their phase (no hoist above the
// wait that guarantees their data). R7 swizzle kept: LDS k-slice sl holds
// global slice sl ^ ((row>>1)&3), conflict-free both sides.
__global__ __launch_bounds__(512, 2) void coding_loss_k(
    const unsigned short* __restrict__ Ag,  // [16384][1024] bf16 = 2*inputs
    const unsigned short* __restrict__ Bg,  // [1024][1024] bf16 = code
    const float* __restrict__ rowsum,       // [1024]
    const int* __restrict__ labels,         // [16384] int32 (normalized)
    float* __restrict__ Z,                  // [4][16384] partial expsums
    float* __restrict__ lin) {              // scalar (zeroed by prep)
  extern __shared__ __align__(16) unsigned short lds[];  // 128 KB dynamic
  // A bufs: lds + q*8192, B bufs: lds + 32768 + q*8192, q = 0..3

  const int t    = threadIdx.x;
  const int lane = t & 63;
  const int w    = t >> 6;   // 0..7
  const int wr   = w >> 2;   // 0..1: rows wr*128..+128
  const int wc   = w & 3;    // 0..3: cols wc*64..+64
  const int g16  = lane >> 4;
  const int c16  = lane & 15;
  const int ct   = blockIdx.x & 3;
  const int rt   = blockIdx.x >> 2;
  const int r0   = rt << 8;
  const int c0   = ct << 8;

  // staging: per K-tile 256 rows x 32 k = 1024 16B-chunks per matrix;
  // 512 threads x 2 issues. Same XOR swizzle as R7.
  size_t a_src[2], b_src[2]; int dstoff[2];
#pragma unroll
  for (int i = 0; i < 2; ++i) {
    int ch = i * 512 + t, row = ch >> 2;
    int sg = (ch & 3) ^ ((row >> 1) & 3);
    a_src[i] = (size_t)(r0 + row) * 1024 + sg * 8;
    b_src[i] = (size_t)(c0 + row) * 1024 + sg * 8;
    dstoff[i] = ch * 8;
  }
  // fragment LDS element offsets (within one buffer)
  int a_eoff[8], b_eoff[4];
#pragma unroll
  for (int i = 0; i < 8; ++i) {
    int ar = wr * 128 + i * 16 + c16;
    a_eoff[i] = ar * 32 + ((g16 ^ ((ar >> 1) & 3)) << 3);
  }
#pragma unroll
  for (int i = 0; i < 4; ++i) {
    int br = wc * 64 + i * 16 + c16;
    b_eoff[i] = br * 32 + ((g16 ^ ((br >> 1) & 3)) << 3);
  }

  f32x4 acc[8][4];
#pragma unroll
  for (int mi = 0; mi < 8; ++mi)
#pragma unroll
    for (int ni = 0; ni < 4; ++ni) acc[mi][ni] = (f32x4)(0.f);

#define TILE(J, DO_STAGE, DO_WAIT, WAIT_IMM)                                    \
  {                                                                             \
    unsigned short* pa = lds + ((J) & 3) * 8192;                                \
    unsigned short* pb = lds + 32768 + ((J) & 3) * 8192;                        \
    unsigned short* sa = lds + (((J) + 3) & 3) * 8192;                          \
    unsigned short* sb = lds + 32768 + (((J) + 3) & 3) * 8192;                  \
    bf16x8 af[4], bv[4];                                                        \
    /* phase 0: frags mi 0-3 + all B; stage A(J+3) */                           \
    _Pragma("unroll") for (int i = 0; i < 4; ++i)                               \
        af[i] = *(const bf16x8*)(pa + a_eoff[i]);                               \
    _Pragma("unroll") for (int i = 0; i < 4; ++i)                               \
        bv[i] = *(const bf16x8*)(pb + b_eoff[i]);                               \
    if (DO_STAGE) {                                                             \
      _Pragma("unroll") for (int i = 0; i < 2; ++i)                             \
          gl2lds16(Ag + a_src[i] + ((J) + 3) * 32, sa + dstoff[i]);             \
    }                                                                           \
    __builtin_amdgcn_s_barrier();                                               \
    __builtin_amdgcn_s_setprio(1);                                              \
    _Pragma("unroll") for (int mi = 0; mi < 4; ++mi)                            \
      _Pragma("unroll") for (int ni = 0; ni < 4; ++ni)                          \
        acc[mi][ni] =                                                           \
            __builtin_amdgcn_mfma_f32_16x16x32_bf16(af[mi], bv[ni], acc[mi][ni], 0, 0, 0); \
    __builtin_amdgcn_s_setprio(0);                                              \
    __builtin_amdgcn_s_barrier();                                               \
    __builtin_amdgcn_sched_barrier(0);                                          \
    /* phase 1: frags mi 4-7 (reuse B regs); stage B(J+3) */                    \
    _Pragma("unroll") for (int i = 0; i < 4; ++i)                               \
        af[i] = *(const bf16x8*)(pa + a_eoff[i + 4]);                           \
    if (DO_STAGE) {                                                             \
      _Pragma("unroll") for (int i = 0; i < 2; ++i)                             \
          gl2lds16(Bg + b_src[i] + ((J) + 3) * 32, sb + dstoff[i]);             \
    }                                                                           \
    __builtin_amdgcn_s_barrier();                                               \
    __builtin_amdgcn_s_setprio(1);                                              \
    _Pragma("unroll") for (int mi = 0; mi < 4; ++mi)                            \
      _Pragma("unroll") for (int ni = 0; ni < 4; ++ni)                          \
        acc[mi + 4][ni] =                                                       \
            __builtin_amdgcn_mfma_f32_16x16x32_bf16(af[mi], bv[ni], acc[mi + 4][ni], 0, 0, 0); \
    __builtin_amdgcn_s_setprio(0);                                              \
    if (DO_WAIT) __builtin_amdgcn_s_waitcnt(WAIT_IMM);                          \
    __builtin_amdgcn_s_barrier();                                               \
    __builtin_amdgcn_sched_barrier(0);                                          \
  }

  // prologue: tiles 0..2 -> bufs 0..2 (12 issues); vmcnt(8) lands tile 0
#pragma unroll
  for (int q = 0; q < 3; ++q) {
#pragma unroll
    for (int i = 0; i < 2; ++i)
      gl2lds16(Ag + a_src[i] + q * 32, lds + q * 8192 + dstoff[i]);
#pragma unroll
    for (int i = 0; i < 2; ++i)
      gl2lds16(Bg + b_src[i] + q * 32, lds + 32768 + q * 8192 + dstoff[i]);
  }
  __builtin_amdgcn_s_waitcnt(0xF78);  // vmcnt(8)
  __builtin_amdgcn_s_barrier();
  __builtin_amdgcn_sched_barrier(0);

#pragma unroll 4
  for (int J = 0; J < 28; ++J) TILE(J, 1, 1, 0xF78);
  TILE(28, 1, 1, 0xF78);             // stages tile 31
  TILE(29, 0, 1, 0xF74);             // vmcnt(4): tile 30 landed
  TILE(30, 0, 1, 0xF70);             // vmcnt(0): tile 31 landed
  TILE(31, 0, 0, 0xF70);
#undef TILE
  __syncthreads();  // drain before aliasing LDS for epilogue

  // ---- epilogue (zbuf aliases the staging LDS) ----
  float* zbuf = (float*)lds;   // [8 waves][128 rows]
  float* lbuf = zbuf + 1024;   // [8]
  float rs[4]; int gcol[4];
#pragma unroll
  for (int ni = 0; ni < 4; ++ni) {
    gcol[ni] = c0 + wc * 64 + ni * 16 + c16;
    rs[ni]   = rowsum[gcol[ni]];
  }
  float lacc = 0.f;  // 0.9*S_label + 1e-4*sum S
#pragma unroll
  for (int mi = 0; mi < 8; ++mi) {
#pragma unroll
    for (int r = 0; r < 4; ++r) {
      int lrow = mi * 16 + g16 * 4 + r;
      int labv = labels[r0 + wr * 128 + lrow];
      float e = 0.f;
#pragma unroll
      for (int ni = 0; ni < 4; ++ni) {
        float S = acc[mi][ni][r] - rs[ni];  // padded cols: S==0, harmless
        e += __expf(S - 40.f);
        lacc += 1e-4f * S;
        if (gcol[ni] == labv) lacc += 0.9f * S;
      }
      e += __shfl_xor(e, 1, 64);
      e += __shfl_xor(e, 2, 64);
      e += __shfl_xor(e, 4, 64);
      e += __shfl_xor(e, 8, 64);
      if (c16 == 0) zbuf[w * 128 + lrow] = e;
    }
  }
#pragma unroll
  for (int d = 1; d < 64; d <<= 1) lacc += __shfl_xor(lacc, d, 64);
  if (lane == 0) lbuf[w] = lacc;
  __syncthreads();
  if (t < 256) {  // row t of the 256-row block: sum the 4 wc wave slices
    int wrg = t >> 7, l7 = t & 127;
    float z = zbuf[(wrg * 4 + 0) * 128 + l7] + zbuf[(wrg * 4 + 1) * 128 + l7] +
              zbuf[(wrg * 4 + 2) * 128 + l7] + zbuf[(wrg * 4 + 3) * 128 + l7];
    Z[ct * 16384 + r0 + t] = z;  // single writer per slot
  }
  if (t == 0)
    atomicAdd(lin, lbuf[0] + lbuf[1] + lbuf[2] + lbuf[3] +
                   lbuf[4] + lbuf[5] + lbuf[6] + lbuf[7]);
}

// out = mean_r(40 + log(sum_ct Z[ct][r])) - lin/16384
__global__ __launch_bounds__(256) void finalize_k(const float* __restrict__ Z,
                                                  const float* __restrict__ lin,
                                                  float* __restrict__ out) {
  int t = threadIdx.x;
  int row = blockIdx.x * 256 + t;
  float v = 40.f + logf(Z[row] + Z[16384 + row] + Z[2 * 16384 + row] + Z[3 * 16384 + row]);
#pragma unroll
  for (int d = 1; d < 64; d <<= 1) v += __shfl_xor(v, d, 64);
  __shared__ float s[4];
  if ((t & 63) == 0) s[t >> 6] = v;
  __syncthreads();
  if (t == 0) {
    float tot = s[0] + s[1] + s[2] + s[3];
    if (blockIdx.x == 0) tot -= lin[0];
    atomicAdd(out, tot * (1.f / 16384.f));
  }
}

extern "C" void kernel_launch(void* const* d_in, const int* in_sizes, int n_in,
                              void* d_out, int out_size, void* d_ws, size_t ws_size,
                              hipStream_t stream) {
  const float* inputs = (const float*)d_in[0];
  const int* labraw   = (const int*)d_in[1];
  const float* code   = (const float*)d_in[2];

  unsigned short* a_bf = (unsigned short*)d_ws;                 // 32 MB
  unsigned short* b_bf = a_bf + (size_t)16384 * 1024;           // 2 MB
  float* rowsum        = (float*)(b_bf + (size_t)1024 * 1024);  // 4 KB
  float* Z             = rowsum + 1024;                         // [4][16384] = 256 KB
  float* lin           = Z + 4 * 16384;                         // 4 B
  int* labs            = (int*)(lin + 1);                       // 64 KB

  static int lds_attr_set = 0;
  if (!lds_attr_set) {
    hipFuncSetAttribute(reinterpret_cast<const void*>(coding_loss_k),
                        hipFuncAttributeMaxDynamicSharedMemorySize, 131072);
    lds_attr_set = 1;
  }

  // 3 graph nodes total (launch overhead was ~half of R7's wall time)
  prep_all_k<<<9280, 256, 0, stream>>>(inputs, labraw, code, a_bf, b_bf, rowsum,
                                       labs, lin, (float*)d_out);
  coding_loss_k<<<256, 512, 131072, stream>>>(a_bf, b_bf, rowsum, labs, Z, lin);
  finalize_k<<<64, 256, 0, stream>>>(Z, lin, (float*)d_out);
}